// Round 3
// baseline (159.093 us; speedup 1.0000x reference)
//
#include <hip/hip_runtime.h>

// TransformerBlockQuantum: [128, 8192, 8] fp32 in/out.
// R3: T=2, launch_bounds(256,4) (was (256,6) -> VGPR=40, ILP-starved).
// Attention restructured into 16 independent (t,k) chains; theta folded into
// q bias; single-pass LN with fused affine; raw v_rsq.

#define NTOK   (128 * 8192)              // 1048576 tokens
#define T      2
#define NTHREADS 256
#define NBLOCKS  (NTOK / (T * NTHREADS)) // 2048
#define TSTRIDE  (NTOK / T)              // 524288
#define LN_EPS 1e-5f

__device__ __forceinline__ float fast_cos(float x) {
    // v_cos_f32 takes revolutions; |x| here is < ~3 revolutions (domain +-256).
    return __builtin_amdgcn_cosf(x * 0.15915494309189535f);
}
__device__ __forceinline__ float fast_rsqrt(float x) {
    return __builtin_amdgcn_rsqf(x);   // v_rsq_f32, ~1ulp of 2^-22 rel err
}

__global__ __launch_bounds__(NTHREADS, 4)
void qtb_kernel(const float* __restrict__ x,
                const float* __restrict__ Wq,  const float* __restrict__ bq,
                const float* __restrict__ tha,
                const float* __restrict__ Wc,  const float* __restrict__ bc,
                const float* __restrict__ g1,  const float* __restrict__ be1,
                const float* __restrict__ thf,
                const float* __restrict__ W1,  const float* __restrict__ b1,
                const float* __restrict__ W2,  const float* __restrict__ b2,
                const float* __restrict__ g2,  const float* __restrict__ be2,
                float* __restrict__ out)
{
    const int g = blockIdx.x * NTHREADS + threadIdx.x;  // 0 .. TSTRIDE-1

    // ---- load x: T tokens * 8 feats, coalesced float4 pairs ----
    float xv[T][8];
#pragma unroll
    for (int t = 0; t < T; ++t) {
        const float4* p = reinterpret_cast<const float4*>(x) + (size_t)(t * TSTRIDE + g) * 2;
        float4 a = p[0];
        float4 b = p[1];
        xv[t][0] = a.x; xv[t][1] = a.y; xv[t][2] = a.z; xv[t][3] = a.w;
        xv[t][4] = b.x; xv[t][5] = b.y; xv[t][6] = b.z; xv[t][7] = b.w;
    }

    // ---- attention: q = x@Wq + (bq+tha); 16 independent accumulator chains ----
    float ca[T][8];
#pragma unroll
    for (int k = 0; k < 8; ++k) {
        float bt = bq[k] + tha[k];
#pragma unroll
        for (int t = 0; t < T; ++t) ca[t][k] = bt;
    }
#pragma unroll
    for (int i = 0; i < 8; ++i) {
        // row i of Wq (contiguous -> s_load_dwordx8)
#pragma unroll
        for (int t = 0; t < T; ++t)
#pragma unroll
            for (int k = 0; k < 8; ++k) ca[t][k] += xv[t][i] * Wq[i * 8 + k];
    }
#pragma unroll
    for (int t = 0; t < T; ++t)
#pragma unroll
        for (int k = 0; k < 8; ++k) ca[t][k] = fast_cos(ca[t][k]);

    // ---- z via cumprods, attn = z@Wc + bc ----
    float attn[T][8];
#pragma unroll
    for (int t = 0; t < T; ++t)
#pragma unroll
        for (int j = 0; j < 8; ++j) attn[t][j] = bc[j];
#pragma unroll
    for (int t = 0; t < T; ++t) {
        float z[8];
        float cp  = ca[t][0];
        float cp1 = 1.0f;
#pragma unroll
        for (int k = 1; k < 8; ++k) {
            cp  *= ca[t][k];
            cp1 *= ca[t][k];
            z[k] = cp;
        }
        z[0] = cp1;
#pragma unroll
        for (int k = 0; k < 8; ++k)
#pragma unroll
            for (int j = 0; j < 8; ++j) attn[t][j] += z[k] * Wc[k * 8 + j];
    }

    // ---- LN1 (fused affine) + zf = cos(thf) * cos(x1) ----
    float cf[8];
#pragma unroll
    for (int j = 0; j < 8; ++j) cf[j] = fast_cos(thf[j]);

    float zf[T][8];
#pragma unroll
    for (int t = 0; t < T; ++t) {
        float y[8];
        float s = 0.f, ss = 0.f;
#pragma unroll
        for (int j = 0; j < 8; ++j) {
            y[j] = xv[t][j] + attn[t][j];
            s  += y[j];
            ss += y[j] * y[j];
        }
        float m = s * 0.125f;
        float r = fast_rsqrt(ss * 0.125f - m * m + LN_EPS);
#pragma unroll
        for (int j = 0; j < 8; ++j) {
            float rg = r * g1[j];
            float x1 = y[j] * rg + (be1[j] - m * rg);
            xv[t][j] = x1;                       // keep x1 for residual 2
            zf[t][j] = cf[j] * fast_cos(x1);
        }
    }

    // ---- FFN: h = relu(zf@W1 + b1); ffn = h@W2 + b2 ----
    float ffn[T][8];
#pragma unroll
    for (int t = 0; t < T; ++t)
#pragma unroll
        for (int j = 0; j < 8; ++j) ffn[t][j] = b2[j];
#pragma unroll
    for (int m = 0; m < 32; ++m) {
#pragma unroll
        for (int t = 0; t < T; ++t) {
            float h = b1[m];
#pragma unroll
            for (int i = 0; i < 8; ++i) h += zf[t][i] * W1[i * 32 + m];
            h = fmaxf(h, 0.f);
#pragma unroll
            for (int j = 0; j < 8; ++j) ffn[t][j] += h * W2[m * 8 + j];
        }
    }

    // ---- LN2 (fused affine) + store ----
#pragma unroll
    for (int t = 0; t < T; ++t) {
        float y[8];
        float s = 0.f, ss = 0.f;
#pragma unroll
        for (int j = 0; j < 8; ++j) {
            y[j] = xv[t][j] + ffn[t][j];
            s  += y[j];
            ss += y[j] * y[j];
        }
        float m = s * 0.125f;
        float r = fast_rsqrt(ss * 0.125f - m * m + LN_EPS);
        float o[8];
#pragma unroll
        for (int j = 0; j < 8; ++j) {
            float rg = r * g2[j];
            o[j] = y[j] * rg + (be2[j] - m * rg);
        }
        float4* q = reinterpret_cast<float4*>(out) + (size_t)(t * TSTRIDE + g) * 2;
        q[0] = make_float4(o[0], o[1], o[2], o[3]);
        q[1] = make_float4(o[4], o[5], o[6], o[7]);
    }
}

extern "C" void kernel_launch(void* const* d_in, const int* in_sizes, int n_in,
                              void* d_out, int out_size, void* d_ws, size_t ws_size,
                              hipStream_t stream) {
    (void)in_sizes; (void)n_in; (void)d_ws; (void)ws_size; (void)out_size;
    qtb_kernel<<<NBLOCKS, NTHREADS, 0, stream>>>(
        (const float*)d_in[0],  // x
        (const float*)d_in[1],  // Wq
        (const float*)d_in[2],  // bq
        (const float*)d_in[3],  // theta_attn
        (const float*)d_in[4],  // Wc
        (const float*)d_in[5],  // bc
        (const float*)d_in[6],  // g1
        (const float*)d_in[7],  // beta1
        (const float*)d_in[8],  // theta_ffn
        (const float*)d_in[9],  // W1
        (const float*)d_in[10], // b1
        (const float*)d_in[11], // W2
        (const float*)d_in[12], // b2
        (const float*)d_in[13], // g2
        (const float*)d_in[14], // beta2
        (float*)d_out);
}

// Round 5
// 122.961 us; speedup vs baseline: 1.2939x; 1.2939x over previous
//
#include <hip/hip_runtime.h>

// TransformerBlockQuantum: [128, 8192, 8] fp32 in/out.
// R5 = R4 with the half2 typedef fixed (__fp16, matching clang builtin sigs).
// Known-good R2 structure (T=2, launch_bounds(256,6)) + v_dot2_f32_f16
// for the three matvecs (q, FFN-in, FFN-out in m-pairs). Weights packed to
// half2 in d_ws by a prep kernel each call. rsqrtf -> raw v_rsq.

#define NTOK   (128 * 8192)              // 1048576 tokens
#define T      2
#define NTHREADS 256
#define NBLOCKS  (NTOK / (T * NTHREADS)) // 2048
#define TSTRIDE  (NTOK / T)              // 524288
#define LN_EPS 1e-5f

typedef __fp16 half2_t __attribute__((ext_vector_type(2)));

union PK { unsigned u; half2_t h; };

__device__ __forceinline__ float fast_cos(float x) {
    // v_cos_f32 takes revolutions; |x| here is < ~3 revolutions (domain +-256).
    return __builtin_amdgcn_cosf(x * 0.15915494309189535f);
}
__device__ __forceinline__ float fast_rsqrt(float x) {
    return __builtin_amdgcn_rsqf(x);
}
__device__ __forceinline__ unsigned packh2(float a, float b) {
    PK c; c.h = __builtin_amdgcn_cvt_pkrtz(a, b); return c.u;
}
__device__ __forceinline__ float dot2(half2_t a, unsigned bw, float c) {
    PK b; b.u = bw;
    return __builtin_amdgcn_fdot2(a, b.h, c, false);
}

// ---- prep: pack weights into half2 pairs (along the K dim of each matvec) ----
// ws layout (uint32): [0,32)  WqP[k][p]  = (Wq[2p][k],   Wq[2p+1][k])
//                     [32,160) W1P[m][p] = (W1[2p][m],   W1[2p+1][m])
//                     [160,288) W2P[mp][j]= (W2[2mp][j], W2[2mp+1][j])
__global__ void pack_weights(const float* __restrict__ Wq,
                             const float* __restrict__ W1,
                             const float* __restrict__ W2,
                             unsigned* __restrict__ ws)
{
    int idx = threadIdx.x;
    if (idx < 32) {
        int k = idx >> 2, p = idx & 3;
        ws[idx] = packh2(Wq[(2 * p) * 8 + k], Wq[(2 * p + 1) * 8 + k]);
    } else if (idx < 160) {
        int i2 = idx - 32;
        int m = i2 >> 2, p = i2 & 3;
        ws[idx] = packh2(W1[(2 * p) * 32 + m], W1[(2 * p + 1) * 32 + m]);
    } else if (idx < 288) {
        int i2 = idx - 160;
        int mp = i2 >> 3, j = i2 & 7;
        ws[idx] = packh2(W2[(2 * mp) * 8 + j], W2[(2 * mp + 1) * 8 + j]);
    }
}

__global__ __launch_bounds__(NTHREADS, 6)
void qtb_kernel(const float* __restrict__ x,
                const float* __restrict__ bq,
                const float* __restrict__ tha,
                const float* __restrict__ Wc,  const float* __restrict__ bc,
                const float* __restrict__ g1,  const float* __restrict__ be1,
                const float* __restrict__ thf,
                const float* __restrict__ b1,
                const float* __restrict__ b2,
                const float* __restrict__ g2,  const float* __restrict__ be2,
                const unsigned* __restrict__ wp,   // packed weights in ws
                float* __restrict__ out)
{
    const int g = blockIdx.x * NTHREADS + threadIdx.x;  // 0 .. TSTRIDE-1

    // ---- load x: T tokens * 8 feats, coalesced float4 pairs; pack i-pairs ----
    float xv[T][8];
    half2_t xp[T][4];
#pragma unroll
    for (int t = 0; t < T; ++t) {
        const float4* p = reinterpret_cast<const float4*>(x) + (size_t)(t * TSTRIDE + g) * 2;
        float4 a = p[0];
        float4 b = p[1];
        xv[t][0] = a.x; xv[t][1] = a.y; xv[t][2] = a.z; xv[t][3] = a.w;
        xv[t][4] = b.x; xv[t][5] = b.y; xv[t][6] = b.z; xv[t][7] = b.w;
        xp[t][0] = __builtin_amdgcn_cvt_pkrtz(a.x, a.y);
        xp[t][1] = __builtin_amdgcn_cvt_pkrtz(a.z, a.w);
        xp[t][2] = __builtin_amdgcn_cvt_pkrtz(b.x, b.y);
        xp[t][3] = __builtin_amdgcn_cvt_pkrtz(b.z, b.w);
    }

    // ---- attention (R2 structure): per k: q via dot2, cos, cumprods, attn fma ----
    float attn[T][8];
#pragma unroll
    for (int t = 0; t < T; ++t)
#pragma unroll
        for (int j = 0; j < 8; ++j) attn[t][j] = bc[j];

    float cp[T];   // running prod ca[0..k]
    float cp1[T];  // running prod ca[1..k]  (for z0)
#pragma unroll
    for (int k = 0; k < 8; ++k) {
        const float bqk = bq[k];
        const float thk = tha[k];
        float wc[8];
#pragma unroll
        for (int j = 0; j < 8; ++j) wc[j] = Wc[k * 8 + j];   // row k of Wc
#pragma unroll
        for (int t = 0; t < T; ++t) {
            float q = bqk;
#pragma unroll
            for (int p = 0; p < 4; ++p) q = dot2(xp[t][p], wp[k * 4 + p], q);
            float ca = fast_cos(q + thk);
            if (k == 0) {
                cp[t] = ca;
                cp1[t] = 1.0f;
            } else {
                cp[t]  *= ca;
                cp1[t] *= ca;
#pragma unroll
                for (int j = 0; j < 8; ++j) attn[t][j] += cp[t] * wc[j];
            }
        }
    }
    // z[0] = prod_{j=1..7} ca_j contributes via Wc row 0
    {
        float wc0[8];
#pragma unroll
        for (int j = 0; j < 8; ++j) wc0[j] = Wc[j];
#pragma unroll
        for (int t = 0; t < T; ++t)
#pragma unroll
            for (int j = 0; j < 8; ++j) attn[t][j] += cp1[t] * wc0[j];
    }

    // ---- LN1 + zf = cos(thf) * cos(x1), packed i-pairs for FFN ----
    float cf[8];
#pragma unroll
    for (int j = 0; j < 8; ++j) cf[j] = fast_cos(thf[j]);
    float sg1[8], sb1[8];
#pragma unroll
    for (int j = 0; j < 8; ++j) { sg1[j] = g1[j]; sb1[j] = be1[j]; }

    half2_t zfp[T][4];
#pragma unroll
    for (int t = 0; t < T; ++t) {
        float y[8];
        float s = 0.f;
#pragma unroll
        for (int j = 0; j < 8; ++j) { y[j] = xv[t][j] + attn[t][j]; s += y[j]; }
        float m = s * 0.125f;
        float v = 0.f;
#pragma unroll
        for (int j = 0; j < 8; ++j) { float d = y[j] - m; v += d * d; }
        float r = fast_rsqrt(v * 0.125f + LN_EPS);
        float zf[8];
#pragma unroll
        for (int j = 0; j < 8; ++j) {
            float x1 = (y[j] - m) * r * sg1[j] + sb1[j];
            xv[t][j] = x1;                       // keep x1 for residual 2
            zf[j] = cf[j] * fast_cos(x1);
        }
#pragma unroll
        for (int p = 0; p < 4; ++p)
            zfp[t][p] = __builtin_amdgcn_cvt_pkrtz(zf[2 * p], zf[2 * p + 1]);
    }

    // ---- FFN via dot2: h-pairs (m,m+1), outer product as dot2 over m-pairs ----
    float ffn[T][8];
    {
        float sb2[8];
#pragma unroll
        for (int j = 0; j < 8; ++j) sb2[j] = b2[j];
#pragma unroll
        for (int t = 0; t < T; ++t)
#pragma unroll
            for (int j = 0; j < 8; ++j) ffn[t][j] = sb2[j];
    }
#pragma unroll
    for (int mp = 0; mp < 16; ++mp) {
        const int m0 = 2 * mp, m1 = 2 * mp + 1;
        const float b1a = b1[m0];
        const float b1b = b1[m1];
        unsigned w2p[8];
#pragma unroll
        for (int j = 0; j < 8; ++j) w2p[j] = wp[160 + mp * 8 + j];
#pragma unroll
        for (int t = 0; t < T; ++t) {
            float h0 = b1a, h1 = b1b;
#pragma unroll
            for (int p = 0; p < 4; ++p) {
                h0 = dot2(zfp[t][p], wp[32 + m0 * 4 + p], h0);
                h1 = dot2(zfp[t][p], wp[32 + m1 * 4 + p], h1);
            }
            h0 = fmaxf(h0, 0.f);
            h1 = fmaxf(h1, 0.f);
            half2_t hp = __builtin_amdgcn_cvt_pkrtz(h0, h1);
#pragma unroll
            for (int j = 0; j < 8; ++j) ffn[t][j] = dot2(hp, w2p[j], ffn[t][j]);
        }
    }

    // ---- LN2 + store ----
    float sg2[8], sbb2[8];
#pragma unroll
    for (int j = 0; j < 8; ++j) { sg2[j] = g2[j]; sbb2[j] = be2[j]; }
#pragma unroll
    for (int t = 0; t < T; ++t) {
        float y[8];
        float s = 0.f;
#pragma unroll
        for (int j = 0; j < 8; ++j) { y[j] = xv[t][j] + ffn[t][j]; s += y[j]; }
        float m = s * 0.125f;
        float v = 0.f;
#pragma unroll
        for (int j = 0; j < 8; ++j) { float d = y[j] - m; v += d * d; }
        float r = fast_rsqrt(v * 0.125f + LN_EPS);
        float o[8];
#pragma unroll
        for (int j = 0; j < 8; ++j) o[j] = (y[j] - m) * r * sg2[j] + sbb2[j];
        float4* q = reinterpret_cast<float4*>(out) + (size_t)(t * TSTRIDE + g) * 2;
        q[0] = make_float4(o[0], o[1], o[2], o[3]);
        q[1] = make_float4(o[4], o[5], o[6], o[7]);
    }
}

extern "C" void kernel_launch(void* const* d_in, const int* in_sizes, int n_in,
                              void* d_out, int out_size, void* d_ws, size_t ws_size,
                              hipStream_t stream) {
    (void)in_sizes; (void)n_in; (void)ws_size; (void)out_size;
    unsigned* wp = (unsigned*)d_ws;
    pack_weights<<<1, 320, 0, stream>>>(
        (const float*)d_in[1],   // Wq
        (const float*)d_in[9],   // W1
        (const float*)d_in[11],  // W2
        wp);
    qtb_kernel<<<NBLOCKS, NTHREADS, 0, stream>>>(
        (const float*)d_in[0],  // x
        (const float*)d_in[2],  // bq
        (const float*)d_in[3],  // theta_attn
        (const float*)d_in[4],  // Wc
        (const float*)d_in[5],  // bc
        (const float*)d_in[6],  // g1
        (const float*)d_in[7],  // beta1
        (const float*)d_in[8],  // theta_ffn
        (const float*)d_in[10], // b1
        (const float*)d_in[12], // b2
        (const float*)d_in[13], // g2
        (const float*)d_in[14], // beta2
        wp,
        (float*)d_out);
}